// Round 11
// baseline (187.951 us; speedup 1.0000x reference)
//
#include <hip/hip_runtime.h>

typedef __bf16 bf16;
typedef __bf16 bf16x8 __attribute__((ext_vector_type(8)));
typedef __bf16 bf16x4 __attribute__((ext_vector_type(4)));
typedef float  f32x4  __attribute__((ext_vector_type(4)));

#define D_MODEL 1024
#define S_LEN   2048
#define NHEAD   16
#define DHEAD   64
#define BATCH   2
#define MROWS   (BATCH * S_LEN)   // 4096

// 0.125 (1/sqrt(dhead)) * log2(e): Q pre-scaled so softmax runs in exp2 domain
#define QSCALE 0.18033688011112042f

// ---- async global->LDS, 16B per lane. lds_base must be wave-uniform; HW
// writes lane i's data at lds_base + i*16 (guide §5 caveat).
__device__ __forceinline__ void gld_lds16(const void* g, void* lds_base) {
    __builtin_amdgcn_global_load_lds(
        (const __attribute__((address_space(1))) void*)g,
        (__attribute__((address_space(3))) void*)lds_base, 16, 0, 0);
}

// ============= prep: transpose+cast 4 weights (z<4) | cast x (z==4) ==========
__global__ void prep_kernel(const float* __restrict__ x,
                            const float* __restrict__ W0, const float* __restrict__ W1,
                            const float* __restrict__ W2, const float* __restrict__ W3,
                            bf16* __restrict__ xb, bf16* __restrict__ Wt) {
    int tx = threadIdx.x, ty = threadIdx.y;   // (32, 8)
    if (blockIdx.z == 4) {
        int tid = ty * 32 + tx;
        size_t base = ((size_t)blockIdx.y * 32 + blockIdx.x) * 4096;
#pragma unroll
        for (int j = 0; j < 4; j++) {
            size_t i = base + (size_t)(j * 256 + tid) * 4;
            f32x4 v = *(const f32x4*)(x + i);
            bf16x4 o;
            o[0] = (bf16)v[0]; o[1] = (bf16)v[1]; o[2] = (bf16)v[2]; o[3] = (bf16)v[3];
            *(bf16x4*)(xb + i) = o;
        }
        return;
    }
    __shared__ float tile[32][33];
    const float* W = (blockIdx.z == 0) ? W0 : (blockIdx.z == 1) ? W1
                   : (blockIdx.z == 2) ? W2 : W3;
    int n0 = blockIdx.x * 32, k0 = blockIdx.y * 32;
#pragma unroll
    for (int j = 0; j < 4; j++)
        tile[ty + 8 * j][tx] = W[(size_t)(k0 + ty + 8 * j) * D_MODEL + n0 + tx];
    __syncthreads();
    bf16* out = Wt + (size_t)blockIdx.z * D_MODEL * D_MODEL;
#pragma unroll
    for (int j = 0; j < 4; j++)
        out[(size_t)(n0 + ty + 8 * j) * D_MODEL + k0 + tx] = (bf16)tile[tx][ty + 8 * j];
}

// ============ gemm0: QKV projections, 8-phase 256^2 schedule (T3+T4) =========
// Round-10 diagnosis: the 2-phase structure sits at its documented ceiling
// (611 TF measured == m233's 607). This kernel ports the proven 8-phase
// template: BM=BN=256, BK=64, 8 waves (2M x 4N), per-wave 128x64 (acc[8][4]).
// Each K-tile = 4 phases; phase q computes quadrant (qa=q>>1, qb=q&1) from
// A-half qa + B-half qb: 12 ds_read_b128 + 16 MFMA, two raw s_barriers.
// LDS 128 KB: [2 slots][2 halves] x (128 rows x 64 k) for A and B. Half
// liveness: A-half0 read phases 0-1, A-half1 2-3, B-half0 0&2, B-half1 1&3.
// Staging stagger (1 half-tile/phase, 2 gld_lds16/wave) into just-died
// regions: (T,0)->A1[T+1], (T,1)->B1[T+1], (T,2)->A0[T+2], (T,3)->B0[T+2].
// A write is safe because the target's last readers completed before the
// previous phase's 2nd barrier (reads are consumed by that phase's MFMAs).
// COUNTED vmcnt(4) once per K-tile (end of phase 3, before 2nd barrier):
// leaves exactly {A0,B0}[T+2] (4 loads) in flight and forces all of tile
// T+1 landed; tail T==14 uses vmcnt(0). Prologue: 6 half-tiles, vmcnt(4).
// Fragment/epilogue index pattern identical to the proven 2-phase kernel,
// only with half-based offsets (row = qa*128 + wm*64 + mi*16 + ..).
// XCD chunking: 192 = 8 x 24; XCD r owns x in [6(r&1),+6), y in [4(r>>1),+4).
__global__ __launch_bounds__(512, 2) void gemm0_kernel(
    const bf16* __restrict__ A, const bf16* __restrict__ Bt,
    const float* __restrict__ b0, const float* __restrict__ b1, const float* __restrict__ b2,
    bf16* __restrict__ Qo, bf16* __restrict__ Ko, bf16* __restrict__ Vto) {
    __shared__ bf16 sA[2][2][128 * 64];   // [slot][half][row][k]  64 KB
    __shared__ bf16 sB[2][2][128 * 64];   // [slot][half][col][k]  64 KB
    const int t = threadIdx.x;
    const int wave = t >> 6, lane = t & 63;
    const int quad = lane >> 4, m16 = lane & 15;
    const int wm = wave >> 2, wn = wave & 3;      // 2M x 4N wave grid
    const int s7 = m16 & 7;
    // ---- XCD-chunked decode: 192 blocks = 8 XCDs x (6x x 4y)
    const int p   = blockIdx.x;
    const int r8  = p & 7;
    const int idx = p >> 3;                // 0..23
    const int xl  = idx % 6, yl = idx / 6;
    const int xb2 = (r8 & 1) * 6 + xl;     // 0..11 (N tiles)
    const int yb2 = (r8 >> 1) * 4 + yl;    // 0..15 (M tiles)
    const int row0 = yb2 * 256, col0 = xb2 * 256;
    constexpr int NKT = D_MODEL / 64;      // 16 K-tiles

    f32x4 acc[8][4];
#pragma unroll
    for (int i = 0; i < 8; i++)
#pragma unroll
        for (int j = 0; j < 4; j++) acc[i][j] = (f32x4){0.f, 0.f, 0.f, 0.f};

    // stage one half-tile (128 rows x 64 k = 16 KB): 2 gld_lds16 per thread.
    // Global k-group pre-swizzled: LDS slot sl of row r holds group sl^(r&7).
    auto stageA = [&](int T, int slot, int h) {
#pragma unroll
        for (int i = 0; i < 2; i++) {
            int cb = i * 512 + wave * 64;
            int c  = cb + lane;
            int r  = c >> 3, sl = c & 7;
            int gk = sl ^ (r & 7);
            gld_lds16(A + (size_t)(row0 + h * 128 + r) * D_MODEL + T * 64 + gk * 8,
                      (char*)&sA[slot][h][0] + cb * 16);
        }
    };
    auto stageB = [&](int T, int slot, int h) {
#pragma unroll
        for (int i = 0; i < 2; i++) {
            int cb = i * 512 + wave * 64;
            int c  = cb + lane;
            int r  = c >> 3, sl = c & 7;
            int gk = sl ^ (r & 7);
            gld_lds16(Bt + (size_t)(col0 + h * 128 + r) * D_MODEL + T * 64 + gk * 8,
                      (char*)&sB[slot][h][0] + cb * 16);
        }
    };

    // prologue: tile 0 fully + tile 1 {A0,B0}; vmcnt(4) leaves the latter in
    // flight and forces tile 0 landed.
    stageA(0, 0, 0); stageB(0, 0, 0);
    stageA(0, 0, 1); stageB(0, 0, 1);
    stageA(1, 1, 0); stageB(1, 1, 0);
    asm volatile("s_waitcnt vmcnt(4)" ::: "memory");
    asm volatile("s_barrier" ::: "memory");

    for (int T = 0; T < NKT; ++T) {
        const int s = T & 1;
#pragma unroll
        for (int q = 0; q < 4; ++q) {
            const int qa = q >> 1, qb = q & 1;   // unrolled -> compile-time
            const bf16* Ah = &sA[s][qa][0];
            const bf16* Bh = &sB[s][qb][0];
            bf16x8 af[4][2], bfr[2][2];
#pragma unroll
            for (int mi = 0; mi < 4; mi++)
#pragma unroll
                for (int kst = 0; kst < 2; kst++)
                    af[mi][kst] = *(const bf16x8*)
                        &Ah[(wm * 64 + mi * 16 + m16) * 64
                            + (((kst * 4 + quad) ^ s7) * 8)];
#pragma unroll
            for (int ni = 0; ni < 2; ni++)
#pragma unroll
                for (int kst = 0; kst < 2; kst++)
                    bfr[ni][kst] = *(const bf16x8*)
                        &Bh[(wn * 32 + ni * 16 + m16) * 64
                            + (((kst * 4 + quad) ^ s7) * 8)];
            // staging stagger (targets died >=1 barrier ago)
            if (q == 0)      { if (T + 1 < NKT) stageA(T + 1, s ^ 1, 1); }
            else if (q == 1) { if (T + 1 < NKT) stageB(T + 1, s ^ 1, 1); }
            else if (q == 2) { if (T + 2 < NKT) stageA(T + 2, s, 0); }
            else             { if (T + 2 < NKT) stageB(T + 2, s, 0); }
            asm volatile("s_barrier" ::: "memory");
            __builtin_amdgcn_s_setprio(1);
#pragma unroll
            for (int kst = 0; kst < 2; kst++)
#pragma unroll
                for (int mi = 0; mi < 4; mi++)
#pragma unroll
                    for (int ni = 0; ni < 2; ni++)
                        acc[qa * 4 + mi][qb * 2 + ni] =
                            __builtin_amdgcn_mfma_f32_16x16x32_bf16(
                                af[mi][kst], bfr[ni][kst],
                                acc[qa * 4 + mi][qb * 2 + ni], 0, 0, 0);
            __builtin_amdgcn_s_setprio(0);
            if (q == 3) {
                if (T < NKT - 2)
                    asm volatile("s_waitcnt vmcnt(4)" ::: "memory");
                else if (T == NKT - 2)
                    asm volatile("s_waitcnt vmcnt(0)" ::: "memory");
            }
            asm volatile("s_barrier" ::: "memory");
        }
    }

    // epilogue (C/D: col = lane&15, row = quad*4 + reg; m89-verified).
    int sel = col0 >> 10;   // uniform per block (1024 % 256 == 0)
    const float* bias_arr = (sel == 0) ? b0 : (sel == 1) ? b1 : b2;
#pragma unroll
    for (int a = 0; a < 8; a++) {
        int ha = a >> 2, mi = a & 3;
        int s0g = row0 + ha * 128 + wm * 64 + mi * 16 + quad * 4;
        int b = s0g >> 11, ss0 = s0g & 2047;
#pragma unroll
        for (int c2 = 0; c2 < 4; c2++) {
            int hb = c2 >> 1, ni = c2 & 1;
            int col = col0 + hb * 128 + wn * 32 + ni * 16 + m16;
            int cn = col & 1023;
            int h = cn >> 6, d = cn & 63;
            float bias = bias_arr[cn];
            if (sel < 2) {
                bf16* dst = (sel == 0) ? Qo : Ko;
                float scl = (sel == 0) ? QSCALE : 1.0f;
                size_t base = (((size_t)b * NHEAD + h) * S_LEN);
#pragma unroll
                for (int r = 0; r < 4; r++)
                    dst[(base + ss0 + r) * DHEAD + d] =
                        (bf16)((acc[a][c2][r] + bias) * scl);
            } else {
                bf16x4 pk;
#pragma unroll
                for (int r = 0; r < 4; r++) pk[r] = (bf16)(acc[a][c2][r] + bias);
                *(bf16x4*)(Vto + (((size_t)b * NHEAD + h) * DHEAD + d) * S_LEN + ss0) = pk;
            }
        }
    }
}

// ======= gemm1: output proj, intra-block split-K + XCD-pinned swizzle ========
// Round-7 structure (proven, no atomics): 512 threads, waves 0-3 (grp 0)
// k=[0,512), waves 4-7 (grp 1) k=[512,1024), triple-buffer, counted vmcnt(3);
// grp 1 parks its partial in LDS scratch, grp 0 adds + bias.
// Bijective XCD-pinning swizzle (round 9, landed): p%8 = y%8 = XCD; per XCD
// = 4 A-panels (1 MB) + full B (2 MB) < 4 MB L2.
__global__ __launch_bounds__(512, 4) void gemm1_kernel(
    const bf16* __restrict__ A, const bf16* __restrict__ Bt,
    const float* __restrict__ bias, float* __restrict__ Co) {
    __shared__ bf16 sA[3][2][128 * 32];
    __shared__ bf16 sB[3][2][64 * 32];
    const int t = threadIdx.x;
    const int wave = t >> 6, lane = t & 63;
    const int quad = lane >> 4, m16 = lane & 15;
    const int grp = wave >> 2, w4 = wave & 3;
    const int wrow = w4 * 32;
    const int p  = blockIdx.x;                    // 0..511
    const int xb = (p >> 3) & 15;                 // col-block 0..15
    const int yb = (p & 7) + 8 * (p >> 7);        // row-block 0..31, y%8 = XCD
    const int row0 = yb * 128, col0 = xb * 64;
    const int kbase = grp * 512;
    constexpr int NK = 16;              // 16 x 32 = 512 k per group

    f32x4 acc[2][4];
#pragma unroll
    for (int i = 0; i < 2; i++)
#pragma unroll
        for (int j = 0; j < 4; j++) acc[i][j] = (f32x4){0.f, 0.f, 0.f, 0.f};

    auto stage = [&](int kk, int buf) {
#pragma unroll
        for (int i = 0; i < 2; i++) {
            int cb = i * 256 + w4 * 64;
            int c  = cb + lane;
            int r  = c >> 2, kg = c & 3;
            int gk = kg ^ ((r >> 1) & 3);
            gld_lds16(A + (size_t)(row0 + r) * D_MODEL + kbase + kk * 32 + gk * 8,
                      (char*)&sA[buf][grp][0] + cb * 16);
        }
        {
            int cb = w4 * 64;
            int c  = cb + lane;
            int r  = c >> 2, kg = c & 3;
            int gk = kg ^ ((r >> 1) & 3);
            gld_lds16(Bt + (size_t)(col0 + r) * D_MODEL + kbase + kk * 32 + gk * 8,
                      (char*)&sB[buf][grp][0] + cb * 16);
        }
    };

    stage(0, 0);
    stage(1, 1);

    const int sx = (m16 >> 1) & 3;
    for (int ks = 0; ks < NK; ++ks) {
        if (ks + 1 < NK)
            asm volatile("s_waitcnt vmcnt(3)\n\ts_barrier" ::: "memory");
        else
            asm volatile("s_waitcnt vmcnt(0)\n\ts_barrier" ::: "memory");
        if (ks + 2 < NK) stage(ks + 2, (ks + 2) % 3);

        const int cur = ks % 3;
        const int gg = (quad ^ sx) * 8;
        bf16x8 af[2], bfr[4];
#pragma unroll
        for (int mi = 0; mi < 2; mi++)
            af[mi] = *(const bf16x8*)&sA[cur][grp][(wrow + mi * 16 + m16) * 32 + gg];
#pragma unroll
        for (int ni = 0; ni < 4; ni++)
            bfr[ni] = *(const bf16x8*)&sB[cur][grp][(ni * 16 + m16) * 32 + gg];
#pragma unroll
        for (int mi = 0; mi < 2; mi++)
#pragma unroll
            for (int ni = 0; ni < 4; ni++)
                acc[mi][ni] = __builtin_amdgcn_mfma_f32_16x16x32_bf16(
                    af[mi], bfr[ni], acc[mi][ni], 0, 0, 0);
    }

    // ---- cross-group reduce via LDS scratch (re-uses staging buffers; all
    // LDS reads of the K-loop completed before the first barrier below).
    __syncthreads();
    float* scr = (float*)&sA[0][0][0];   // 128 x 66 f32 = 33.8 KB < 48 KB
    if (grp == 1) {
#pragma unroll
        for (int mi = 0; mi < 2; mi++)
#pragma unroll
            for (int ni = 0; ni < 4; ni++)
#pragma unroll
                for (int r = 0; r < 4; r++)
                    scr[(wrow + mi * 16 + quad * 4 + r) * 66 + ni * 16 + m16] =
                        acc[mi][ni][r];
    }
    __syncthreads();
    if (grp == 0) {
#pragma unroll
        for (int mi = 0; mi < 2; mi++)
#pragma unroll
            for (int ni = 0; ni < 4; ni++) {
                int col = col0 + ni * 16 + m16;
                float bb = bias[col];
#pragma unroll
                for (int r = 0; r < 4; r++) {
                    int row = wrow + mi * 16 + quad * 4 + r;
                    Co[(size_t)(row0 + row) * D_MODEL + col] =
                        acc[mi][ni][r] + scr[row * 66 + ni * 16 + m16] + bb;
                }
            }
    }
}

// ======================= flash attention (causal) ============================
// One block per (head, q-tile): grid 32x32 = 1024 blocks -> 4 blocks/CU.
// Double-buffered KV staging, prefetch depth 1; head->XCD pinning via
// blockIdx.x = bh; LPT via qt = 31-blockIdx.y. Transposed scores, per-lane
// softmax in exp2 domain, in-register P via p32+p16 double swap; V-fragment
// is the conflict-tuned ds_read_b128 from XOR-swizzled Vt_s (0 conflicts).
__global__ __launch_bounds__(256, 4) void attn_kernel(
    const bf16* __restrict__ Q, const bf16* __restrict__ K,
    const bf16* __restrict__ Vt, bf16* __restrict__ ctx) {
    __shared__ bf16 Kt_s[2][64 * 64];
    __shared__ bf16 Vt_s[2][64 * 64];

    const int t = threadIdx.x, wave = t >> 6, lane = t & 63;
    const int quad = lane >> 4, m16 = lane & 15;
    const int bh = blockIdx.x;            // head -> XCD bh%8 (L2 KV locality)
    const int qt = 31 - blockIdx.y;       // big tiles first (LPT)
    const int nt = qt + 1;                // causal KV tiles (64-wide)
    const size_t base = (size_t)bh * S_LEN * DHEAD;

    // Q fragments (B-operand), kept in regs
    bf16x8 aq[2];
#pragma unroll
    for (int kst = 0; kst < 2; kst++)
        aq[kst] = *(const bf16x8*)(Q + base
            + (size_t)(qt * 64 + wave * 16 + m16) * DHEAD + kst * 32 + quad * 8);

    f32x4 o[4];
#pragma unroll
    for (int di = 0; di < 4; di++) o[di] = (f32x4){0.f, 0.f, 0.f, 0.f};
    float l_acc = 0.f;

    auto stage = [&](int j, int buf) {
#pragma unroll
        for (int i = 0; i < 2; i++) {
            int cb = i * 256 + wave * 64;
            int c  = cb + lane;
            int pos = c >> 3, g = c & 7;
            int gk = g ^ (pos & 7);
            gld_lds16(K  + base + (size_t)(j * 64 + pos) * DHEAD + gk * 8,
                      (char*)&Kt_s[buf][0] + cb * 16);
            gld_lds16(Vt + base + (size_t)pos * S_LEN + j * 64 + gk * 8,
                      (char*)&Vt_s[buf][0] + cb * 16);
        }
    };

    stage(0, 0);

    for (int j = 0; j < nt; ++j) {
        asm volatile("s_waitcnt vmcnt(0)\n\ts_barrier" ::: "memory");
        if (j + 1 < nt) stage(j + 1, (j + 1) & 1);

        const int cur = j & 1;
        const int kt0 = j * 64;

        // ---- scores S^T[kpos][q] = K @ Q^T
        f32x4 sc[4];
#pragma unroll
        for (int ni = 0; ni < 4; ni++) sc[ni] = (f32x4){0.f, 0.f, 0.f, 0.f};
        __builtin_amdgcn_s_setprio(1);
#pragma unroll
        for (int ni = 0; ni < 4; ni++) {
            int pos = ni * 16 + m16;
#pragma unroll
            for (int kst = 0; kst < 2; kst++) {
                int gg = (kst * 4 + quad) ^ (pos & 7);
                bf16x8 kf = *(const bf16x8*)&Kt_s[cur][pos * 64 + gg * 8];
                sc[ni] = __builtin_amdgcn_mfma_f32_16x16x32_bf16(
                    kf, aq[kst], sc[ni], 0, 0, 0);
            }
        }
        __builtin_amdgcn_s_setprio(0);

        // ---- causal mask: only on the diagonal tile
        if (j == qt) {
            int qg = qt * 64 + wave * 16 + m16;
#pragma unroll
            for (int ni = 0; ni < 4; ni++)
#pragma unroll
                for (int r = 0; r < 4; r++) {
                    int kp = kt0 + ni * 16 + quad * 4 + r;
                    if (kp > qg) sc[ni][r] = -1e9f;
                }
        }

        // ---- p = exp2(s); accumulate l; pack bf16 dwords in-register.
        unsigned int pd[4][2];
        {
            float ls0 = 0.f, ls1 = 0.f;
#pragma unroll
            for (int ni = 0; ni < 4; ni++) {
                float p0 = __builtin_amdgcn_exp2f(sc[ni][0]);
                float p1 = __builtin_amdgcn_exp2f(sc[ni][1]);
                float p2 = __builtin_amdgcn_exp2f(sc[ni][2]);
                float p3 = __builtin_amdgcn_exp2f(sc[ni][3]);
                union { bf16x4 h; unsigned int u[2]; } cv;
                cv.h[0] = (bf16)p0; cv.h[1] = (bf16)p1;
                cv.h[2] = (bf16)p2; cv.h[3] = (bf16)p3;
                pd[ni][0] = cv.u[0];
                pd[ni][1] = cv.u[1];
                ls0 += p0 + p1;
                ls1 += p2 + p3;
            }
            l_acc += ls0 + ls1;
        }

        // ---- O^T += (P @ V)^T, natural k order via p32+p16 double swap
#pragma unroll
        for (int kst = 0; kst < 2; kst++) {
            unsigned int x0 = pd[2 * kst][0],     y0 = pd[2 * kst][1];
            unsigned int x1 = pd[2 * kst + 1][0], y1 = pd[2 * kst + 1][1];
            asm("v_permlane32_swap_b32 %0, %1" : "+v"(x0), "+v"(x1));
            asm("v_permlane32_swap_b32 %0, %1" : "+v"(y0), "+v"(y1));
            asm("v_permlane16_swap_b32 %0, %1" : "+v"(x0), "+v"(x1));
            asm("v_permlane16_swap_b32 %0, %1" : "+v"(y0), "+v"(y1));
            union { unsigned int u[4]; bf16x8 v; } pk;
            pk.u[0] = x0; pk.u[1] = y0; pk.u[2] = x1; pk.u[3] = y1;
            bf16x8 ap = pk.v;
            __builtin_amdgcn_s_setprio(1);
#pragma unroll
            for (int di = 0; di < 4; di++) {
                int d = di * 16 + m16;
                int gg = (kst * 4 + quad) ^ (d & 7);
                bf16x8 vf = *(const bf16x8*)&Vt_s[cur][d * 64 + gg * 8];
                o[di] = __builtin_amdgcn_mfma_f32_16x16x32_bf16(
                    vf, ap, o[di], 0, 0, 0);
            }
            __builtin_amdgcn_s_setprio(0);
        }
    }

    // ---- final l reduction + normalize + write ctx [B,S,1024] bf16
    int b = bh >> 4, h = bh & 15;
    float l = l_acc;
    l += __shfl_xor(l, 16);
    l += __shfl_xor(l, 32);
    float rl = 1.0f / l;
    int s = qt * 64 + wave * 16 + m16;
#pragma unroll
    for (int di = 0; di < 4; di++) {
        bf16x4 pk;
#pragma unroll
        for (int r = 0; r < 4; r++) pk[r] = (bf16)(o[di][r] * rl);
        *(bf16x4*)(ctx + ((size_t)b * S_LEN + s) * D_MODEL
                   + h * DHEAD + di * 16 + quad * 4) = pk;
    }
}

// ================================ launch =====================================
extern "C" void kernel_launch(void* const* d_in, const int* in_sizes, int n_in,
                              void* d_out, int out_size, void* d_ws, size_t ws_size,
                              hipStream_t stream) {
    const float* x  = (const float*)d_in[0];
    const float* Wq = (const float*)d_in[1];
    const float* bq = (const float*)d_in[2];
    const float* Wk = (const float*)d_in[3];
    const float* bk = (const float*)d_in[4];
    const float* Wv = (const float*)d_in[5];
    const float* bv = (const float*)d_in[6];
    const float* Wo = (const float*)d_in[7];
    const float* bo = (const float*)d_in[8];
    float* out = (float*)d_out;

    char* ws = (char*)d_ws;
    const size_t MB = 1u << 20;
    bf16* xb  = (bf16*)(ws + 0);         // 8 MB  [4096,1024]
    bf16* Wt  = (bf16*)(ws + 8  * MB);   // 8 MB  [4][1024][1024]
    bf16* Qb  = (bf16*)(ws + 16 * MB);   // 8 MB  [B,H,S,64]  (pre-scaled by QSCALE)
    bf16* Kb  = (bf16*)(ws + 24 * MB);   // 8 MB  [B,H,S,64]
    bf16* Vtb = (bf16*)(ws + 32 * MB);   // 8 MB  [B,H,64,S]
    bf16* ctx = (bf16*)(ws + 0);         // reuse xb region (dead after QKV GEMM)

    prep_kernel<<<dim3(32, 32, 5), dim3(32, 8), 0, stream>>>(x, Wq, Wk, Wv, Wo,
                                                             xb, Wt);
    gemm0_kernel<<<dim3(192), 512, 0, stream>>>(xb, Wt, bq, bk, bv,
                                                Qb, Kb, Vtb);
    attn_kernel<<<dim3(32, 32), 256, 0, stream>>>(Qb, Kb, Vtb, ctx);
    gemm1_kernel<<<dim3(512), 512, 0, stream>>>(ctx, Wt + 3 * 1024 * 1024,
                                                bo, out);
}

// Round 13
// 175.243 us; speedup vs baseline: 1.0725x; 1.0725x over previous
//
#include <hip/hip_runtime.h>

typedef __bf16 bf16;
typedef __bf16 bf16x8 __attribute__((ext_vector_type(8)));
typedef __bf16 bf16x4 __attribute__((ext_vector_type(4)));
typedef float  f32x4  __attribute__((ext_vector_type(4)));

#define D_MODEL 1024
#define S_LEN   2048
#define NHEAD   16
#define DHEAD   64
#define BATCH   2
#define MROWS   (BATCH * S_LEN)   // 4096

// 0.125 (1/sqrt(dhead)) * log2(e): Q pre-scaled so softmax runs in exp2 domain
#define QSCALE 0.18033688011112042f

// ---- async global->LDS, 16B per lane. lds_base must be wave-uniform; HW
// writes lane i's data at lds_base + i*16 (guide §5 caveat).
__device__ __forceinline__ void gld_lds16(const void* g, void* lds_base) {
    __builtin_amdgcn_global_load_lds(
        (const __attribute__((address_space(1))) void*)g,
        (__attribute__((address_space(3))) void*)lds_base, 16, 0, 0);
}

// ============= prep: transpose+cast 4 weights (z<4) | cast x (z==4) ==========
__global__ void prep_kernel(const float* __restrict__ x,
                            const float* __restrict__ W0, const float* __restrict__ W1,
                            const float* __restrict__ W2, const float* __restrict__ W3,
                            bf16* __restrict__ xb, bf16* __restrict__ Wt) {
    int tx = threadIdx.x, ty = threadIdx.y;   // (32, 8)
    if (blockIdx.z == 4) {
        int tid = ty * 32 + tx;
        size_t base = ((size_t)blockIdx.y * 32 + blockIdx.x) * 4096;
#pragma unroll
        for (int j = 0; j < 4; j++) {
            size_t i = base + (size_t)(j * 256 + tid) * 4;
            f32x4 v = *(const f32x4*)(x + i);
            bf16x4 o;
            o[0] = (bf16)v[0]; o[1] = (bf16)v[1]; o[2] = (bf16)v[2]; o[3] = (bf16)v[3];
            *(bf16x4*)(xb + i) = o;
        }
        return;
    }
    __shared__ float tile[32][33];
    const float* W = (blockIdx.z == 0) ? W0 : (blockIdx.z == 1) ? W1
                   : (blockIdx.z == 2) ? W2 : W3;
    int n0 = blockIdx.x * 32, k0 = blockIdx.y * 32;
#pragma unroll
    for (int j = 0; j < 4; j++)
        tile[ty + 8 * j][tx] = W[(size_t)(k0 + ty + 8 * j) * D_MODEL + n0 + tx];
    __syncthreads();
    bf16* out = Wt + (size_t)blockIdx.z * D_MODEL * D_MODEL;
#pragma unroll
    for (int j = 0; j < 4; j++)
        out[(size_t)(n0 + ty + 8 * j) * D_MODEL + k0 + tx] = (bf16)tile[tx][ty + 8 * j];
}

// ====== gemm0: 8-phase 256^2, GRAY-CODE phases + register-held fragments =====
// Round-11 post-mortem: the (0,0)(0,1)(1,0)(1,1) phase order re-read every
// fragment -> 48 ds_read_b128/wave/K-tile = 4608 LDS cyc/K-tile/CU vs 614
// MFMA cyc: LDS-read-bound at 1.7x the template's traffic (this model
// reproduces m201's 1563 TF exactly: 28 reads -> 3300 cyc/K-tile).
// Fix = the template's read economy: Gray order (0,0)->(0,1)->(1,1)->(1,0);
// A-frags held in regs across phases 0-1 and 2-3; B1 held across 1-2; only
// B0 re-read (ph3). 28 reads/K-tile (12,4,8,4 per phase).
// Stagger (slot-aware; every write >=1 barrier after target's last LDS read;
// A0[T] is LDS-read at ph0 only, A1[T] at ph2 only, B0[T] ph0+ph3, B1[T] ph1,
// all then register-held): ph0 -> B1[T+1] (old died T-1 ph1), ph1 -> B0[T+1]
// (old died T-1 ph3), ph2 -> A0[T+2] into slot s (A0[T] read done in ph0),
// ph3 -> A1[T+1] (old died T-1 ph2).
// COUNTED vmcnt(4) twice per K-tile: end-ph1 (leaves B1/B0[T+1] in flight;
// forces A0[T+1] (T-1 ph2) + A1[T] (T-1 ph3) landed -- A1[T] is read at ph2);
// end-ph3 (leaves A0[T+2]/A1[T+1]; forces B1/B0[T+1] landed for T+1 ph0/1).
// Last 2 tiles: vmcnt(0). Prologue: tile0 all 4 halves + A0[1], vmcnt(2).
// XCD chunking: 192 = 8 x 24; XCD r owns x in [6(r&1),+6), y in [4(r>>1),+4).
__global__ __launch_bounds__(512, 2) void gemm0_kernel(
    const bf16* __restrict__ A, const bf16* __restrict__ Bt,
    const float* __restrict__ b0, const float* __restrict__ b1, const float* __restrict__ b2,
    bf16* __restrict__ Qo, bf16* __restrict__ Ko, bf16* __restrict__ Vto) {
    __shared__ bf16 sA[2][2][128 * 64];   // [slot][half][row][k]  64 KB
    __shared__ bf16 sB[2][2][128 * 64];   // [slot][half][col][k]  64 KB
    const int t = threadIdx.x;
    const int wave = t >> 6, lane = t & 63;
    const int quad = lane >> 4, m16 = lane & 15;
    const int wm = wave >> 2, wn = wave & 3;      // 2M x 4N wave grid
    const int s7 = m16 & 7;
    // ---- XCD-chunked decode: 192 blocks = 8 XCDs x (6x x 4y)
    const int p   = blockIdx.x;
    const int r8  = p & 7;
    const int idx = p >> 3;                // 0..23
    const int xl  = idx % 6, yl = idx / 6;
    const int xb2 = (r8 & 1) * 6 + xl;     // 0..11 (N tiles)
    const int yb2 = (r8 >> 1) * 4 + yl;    // 0..15 (M tiles)
    const int row0 = yb2 * 256, col0 = xb2 * 256;
    constexpr int NKT = D_MODEL / 64;      // 16 K-tiles

    f32x4 acc[8][4];
#pragma unroll
    for (int i = 0; i < 8; i++)
#pragma unroll
        for (int j = 0; j < 4; j++) acc[i][j] = (f32x4){0.f, 0.f, 0.f, 0.f};

    // stage one half-tile (128 rows x 64 k = 16 KB): 2 gld_lds16 per thread.
    // Global k-group pre-swizzled: LDS slot sl of row r holds group sl^(r&7).
    auto stageA = [&](int T, int slot, int h) {
#pragma unroll
        for (int i = 0; i < 2; i++) {
            int cb = i * 512 + wave * 64;
            int c  = cb + lane;
            int r  = c >> 3, sl = c & 7;
            int gk = sl ^ (r & 7);
            gld_lds16(A + (size_t)(row0 + h * 128 + r) * D_MODEL + T * 64 + gk * 8,
                      (char*)&sA[slot][h][0] + cb * 16);
        }
    };
    auto stageB = [&](int T, int slot, int h) {
#pragma unroll
        for (int i = 0; i < 2; i++) {
            int cb = i * 512 + wave * 64;
            int c  = cb + lane;
            int r  = c >> 3, sl = c & 7;
            int gk = sl ^ (r & 7);
            gld_lds16(Bt + (size_t)(col0 + h * 128 + r) * D_MODEL + T * 64 + gk * 8,
                      (char*)&sB[slot][h][0] + cb * 16);
        }
    };

#define RD_A(AF, AH)                                                        \
    _Pragma("unroll") for (int mi = 0; mi < 4; mi++)                        \
    _Pragma("unroll") for (int kst = 0; kst < 2; kst++)                     \
        AF[mi][kst] = *(const bf16x8*)                                      \
            &(AH)[(wm * 64 + mi * 16 + m16) * 64 + (((kst * 4 + quad) ^ s7) * 8)];
#define RD_B(BF, BH)                                                        \
    _Pragma("unroll") for (int ni = 0; ni < 2; ni++)                        \
    _Pragma("unroll") for (int kst = 0; kst < 2; kst++)                     \
        BF[ni][kst] = *(const bf16x8*)                                      \
            &(BH)[(wn * 32 + ni * 16 + m16) * 64 + (((kst * 4 + quad) ^ s7) * 8)];
#define MMQ(AM, BN)                                                         \
    _Pragma("unroll") for (int kst = 0; kst < 2; kst++)                     \
    _Pragma("unroll") for (int mi = 0; mi < 4; mi++)                        \
    _Pragma("unroll") for (int ni = 0; ni < 2; ni++)                        \
        acc[(AM) + mi][(BN) + ni] = __builtin_amdgcn_mfma_f32_16x16x32_bf16(\
            af[mi][kst], bfr[ni][kst], acc[(AM) + mi][(BN) + ni], 0, 0, 0);
#define BAR() asm volatile("s_barrier" ::: "memory")

    // prologue: tile 0 fully + A0[1]; vmcnt(2) leaves A0[1] in flight.
    stageA(0, 0, 0); stageB(0, 0, 0);
    stageA(0, 0, 1); stageB(0, 0, 1);
    stageA(1, 1, 0);
    asm volatile("s_waitcnt vmcnt(2)" ::: "memory");
    BAR();

    for (int T = 0; T < NKT; ++T) {
        const int s = T & 1;
        const bf16* A0h = &sA[s][0][0];
        const bf16* A1h = &sA[s][1][0];
        const bf16* B0h = &sB[s][0][0];
        const bf16* B1h = &sB[s][1][0];
        bf16x8 af[4][2], bfr[2][2];

        // ---- phase 0: quadrant (0,0) -- read A0 + B0
        RD_A(af, A0h); RD_B(bfr, B0h);
        if (T + 1 < NKT) stageB(T + 1, s ^ 1, 1);     // B1[T+1]
        BAR();
        __builtin_amdgcn_s_setprio(1);
        MMQ(0, 0);
        __builtin_amdgcn_s_setprio(0);
        BAR();

        // ---- phase 1: quadrant (0,1) -- read B1 (af kept)
        RD_B(bfr, B1h);
        if (T + 1 < NKT) stageB(T + 1, s ^ 1, 0);     // B0[T+1]
        BAR();
        __builtin_amdgcn_s_setprio(1);
        MMQ(0, 2);
        __builtin_amdgcn_s_setprio(0);
        if (T < NKT - 2) asm volatile("s_waitcnt vmcnt(4)" ::: "memory");
        else             asm volatile("s_waitcnt vmcnt(0)" ::: "memory");
        BAR();

        // ---- phase 2: quadrant (1,1) -- read A1 (bfr kept)
        RD_A(af, A1h);
        if (T + 2 < NKT) stageA(T + 2, s, 0);         // A0[T+2], slot s
        BAR();
        __builtin_amdgcn_s_setprio(1);
        MMQ(4, 2);
        __builtin_amdgcn_s_setprio(0);
        BAR();

        // ---- phase 3: quadrant (1,0) -- read B0 (af kept)
        RD_B(bfr, B0h);
        if (T + 1 < NKT) stageA(T + 1, s ^ 1, 1);     // A1[T+1]
        BAR();
        __builtin_amdgcn_s_setprio(1);
        MMQ(4, 0);
        __builtin_amdgcn_s_setprio(0);
        if (T < NKT - 2) asm volatile("s_waitcnt vmcnt(4)" ::: "memory");
        else             asm volatile("s_waitcnt vmcnt(0)" ::: "memory");
        BAR();
    }
#undef RD_A
#undef RD_B
#undef MMQ
#undef BAR

    // epilogue (C/D: col = lane&15, row = quad*4 + reg; m89-verified).
    int sel = col0 >> 10;   // uniform per block (1024 % 256 == 0)
    const float* bias_arr = (sel == 0) ? b0 : (sel == 1) ? b1 : b2;
#pragma unroll
    for (int a = 0; a < 8; a++) {
        int ha = a >> 2, mi = a & 3;
        int s0g = row0 + ha * 128 + wm * 64 + mi * 16 + quad * 4;
        int b = s0g >> 11, ss0 = s0g & 2047;
#pragma unroll
        for (int c2 = 0; c2 < 4; c2++) {
            int hb = c2 >> 1, ni = c2 & 1;
            int col = col0 + hb * 128 + wn * 32 + ni * 16 + m16;
            int cn = col & 1023;
            int h = cn >> 6, d = cn & 63;
            float bias = bias_arr[cn];
            if (sel < 2) {
                bf16* dst = (sel == 0) ? Qo : Ko;
                float scl = (sel == 0) ? QSCALE : 1.0f;
                size_t base = (((size_t)b * NHEAD + h) * S_LEN);
#pragma unroll
                for (int r = 0; r < 4; r++)
                    dst[(base + ss0 + r) * DHEAD + d] =
                        (bf16)((acc[a][c2][r] + bias) * scl);
            } else {
                bf16x4 pk;
#pragma unroll
                for (int r = 0; r < 4; r++) pk[r] = (bf16)(acc[a][c2][r] + bias);
                *(bf16x4*)(Vto + (((size_t)b * NHEAD + h) * DHEAD + d) * S_LEN + ss0) = pk;
            }
        }
    }
}

// ======= gemm1: output proj, intra-block split-K + XCD-pinned swizzle ========
// Round-7 structure (proven, no atomics): 512 threads, waves 0-3 (grp 0)
// k=[0,512), waves 4-7 (grp 1) k=[512,1024), triple-buffer, counted vmcnt(3);
// grp 1 parks its partial in LDS scratch, grp 0 adds + bias.
// Bijective XCD-pinning swizzle (round 9, landed): p%8 = y%8 = XCD; per XCD
// = 4 A-panels (1 MB) + full B (2 MB) < 4 MB L2.
__global__ __launch_bounds__(512, 4) void gemm1_kernel(
    const bf16* __restrict__ A, const bf16* __restrict__ Bt,
    const float* __restrict__ bias, float* __restrict__ Co) {
    __shared__ bf16 sA[3][2][128 * 32];
    __shared__ bf16 sB[3][2][64 * 32];
    const int t = threadIdx.x;
    const int wave = t >> 6, lane = t & 63;
    const int quad = lane >> 4, m16 = lane & 15;
    const int grp = wave >> 2, w4 = wave & 3;
    const int wrow = w4 * 32;
    const int p  = blockIdx.x;                    // 0..511
    const int xb = (p >> 3) & 15;                 // col-block 0..15
    const int yb = (p & 7) + 8 * (p >> 7);        // row-block 0..31, y%8 = XCD
    const int row0 = yb * 128, col0 = xb * 64;
    const int kbase = grp * 512;
    constexpr int NK = 16;              // 16 x 32 = 512 k per group

    f32x4 acc[2][4];
#pragma unroll
    for (int i = 0; i < 2; i++)
#pragma unroll
        for (int j = 0; j < 4; j++) acc[i][j] = (f32x4){0.f, 0.f, 0.f, 0.f};

    auto stage = [&](int kk, int buf) {
#pragma unroll
        for (int i = 0; i < 2; i++) {
            int cb = i * 256 + w4 * 64;
            int c  = cb + lane;
            int r  = c >> 2, kg = c & 3;
            int gk = kg ^ ((r >> 1) & 3);
            gld_lds16(A + (size_t)(row0 + r) * D_MODEL + kbase + kk * 32 + gk * 8,
                      (char*)&sA[buf][grp][0] + cb * 16);
        }
        {
            int cb = w4 * 64;
            int c  = cb + lane;
            int r  = c >> 2, kg = c & 3;
            int gk = kg ^ ((r >> 1) & 3);
            gld_lds16(Bt + (size_t)(col0 + r) * D_MODEL + kbase + kk * 32 + gk * 8,
                      (char*)&sB[buf][grp][0] + cb * 16);
        }
    };

    stage(0, 0);
    stage(1, 1);

    const int sx = (m16 >> 1) & 3;
    for (int ks = 0; ks < NK; ++ks) {
        if (ks + 1 < NK)
            asm volatile("s_waitcnt vmcnt(3)\n\ts_barrier" ::: "memory");
        else
            asm volatile("s_waitcnt vmcnt(0)\n\ts_barrier" ::: "memory");
        if (ks + 2 < NK) stage(ks + 2, (ks + 2) % 3);

        const int cur = ks % 3;
        const int gg = (quad ^ sx) * 8;
        bf16x8 af[2], bfr[4];
#pragma unroll
        for (int mi = 0; mi < 2; mi++)
            af[mi] = *(const bf16x8*)&sA[cur][grp][(wrow + mi * 16 + m16) * 32 + gg];
#pragma unroll
        for (int ni = 0; ni < 4; ni++)
            bfr[ni] = *(const bf16x8*)&sB[cur][grp][(ni * 16 + m16) * 32 + gg];
#pragma unroll
        for (int mi = 0; mi < 2; mi++)
#pragma unroll
            for (int ni = 0; ni < 4; ni++)
                acc[mi][ni] = __builtin_amdgcn_mfma_f32_16x16x32_bf16(
                    af[mi], bfr[ni], acc[mi][ni], 0, 0, 0);
    }

    // ---- cross-group reduce via LDS scratch (re-uses staging buffers; all
    // LDS reads of the K-loop completed before the first barrier below).
    __syncthreads();
    float* scr = (float*)&sA[0][0][0];   // 128 x 66 f32 = 33.8 KB < 48 KB
    if (grp == 1) {
#pragma unroll
        for (int mi = 0; mi < 2; mi++)
#pragma unroll
            for (int ni = 0; ni < 4; ni++)
#pragma unroll
                for (int r = 0; r < 4; r++)
                    scr[(wrow + mi * 16 + quad * 4 + r) * 66 + ni * 16 + m16] =
                        acc[mi][ni][r];
    }
    __syncthreads();
    if (grp == 0) {
#pragma unroll
        for (int mi = 0; mi < 2; mi++)
#pragma unroll
            for (int ni = 0; ni < 4; ni++) {
                int col = col0 + ni * 16 + m16;
                float bb = bias[col];
#pragma unroll
                for (int r = 0; r < 4; r++) {
                    int row = wrow + mi * 16 + quad * 4 + r;
                    Co[(size_t)(row0 + row) * D_MODEL + col] =
                        acc[mi][ni][r] + scr[row * 66 + ni * 16 + m16] + bb;
                }
            }
    }
}

// ======================= flash attention (causal) ============================
// One block per (head, q-tile): grid 32x32 = 1024 blocks -> 4 blocks/CU.
// Double-buffered KV staging, prefetch depth 1; head->XCD pinning via
// blockIdx.x = bh; LPT via qt = 31-blockIdx.y. Transposed scores, per-lane
// softmax in exp2 domain, in-register P via p32+p16 double swap; V-fragment
// is the conflict-tuned ds_read_b128 from XOR-swizzled Vt_s (0 conflicts).
__global__ __launch_bounds__(256, 4) void attn_kernel(
    const bf16* __restrict__ Q, const bf16* __restrict__ K,
    const bf16* __restrict__ Vt, bf16* __restrict__ ctx) {
    __shared__ bf16 Kt_s[2][64 * 64];
    __shared__ bf16 Vt_s[2][64 * 64];

    const int t = threadIdx.x, wave = t >> 6, lane = t & 63;
    const int quad = lane >> 4, m16 = lane & 15;
    const int bh = blockIdx.x;            // head -> XCD bh%8 (L2 KV locality)
    const int qt = 31 - blockIdx.y;       // big tiles first (LPT)
    const int nt = qt + 1;                // causal KV tiles (64-wide)
    const size_t base = (size_t)bh * S_LEN * DHEAD;

    // Q fragments (B-operand), kept in regs
    bf16x8 aq[2];
#pragma unroll
    for (int kst = 0; kst < 2; kst++)
        aq[kst] = *(const bf16x8*)(Q + base
            + (size_t)(qt * 64 + wave * 16 + m16) * DHEAD + kst * 32 + quad * 8);

    f32x4 o[4];
#pragma unroll
    for (int di = 0; di < 4; di++) o[di] = (f32x4){0.f, 0.f, 0.f, 0.f};
    float l_acc = 0.f;

    auto stage = [&](int j, int buf) {
#pragma unroll
        for (int i = 0; i < 2; i++) {
            int cb = i * 256 + wave * 64;
            int c  = cb + lane;
            int pos = c >> 3, g = c & 7;
            int gk = g ^ (pos & 7);
            gld_lds16(K  + base + (size_t)(j * 64 + pos) * DHEAD + gk * 8,
                      (char*)&Kt_s[buf][0] + cb * 16);
            gld_lds16(Vt + base + (size_t)pos * S_LEN + j * 64 + gk * 8,
                      (char*)&Vt_s[buf][0] + cb * 16);
        }
    };

    stage(0, 0);

    for (int j = 0; j < nt; ++j) {
        asm volatile("s_waitcnt vmcnt(0)\n\ts_barrier" ::: "memory");
        if (j + 1 < nt) stage(j + 1, (j + 1) & 1);

        const int cur = j & 1;
        const int kt0 = j * 64;

        // ---- scores S^T[kpos][q] = K @ Q^T
        f32x4 sc[4];
#pragma unroll
        for (int ni = 0; ni < 4; ni++) sc[ni] = (f32x4){0.f, 0.f, 0.f, 0.f};
        __builtin_amdgcn_s_setprio(1);
#pragma unroll
        for (int ni = 0; ni < 4; ni++) {
            int pos = ni * 16 + m16;
#pragma unroll
            for (int kst = 0; kst < 2; kst++) {
                int gg = (kst * 4 + quad) ^ (pos & 7);
                bf16x8 kf = *(const bf16x8*)&Kt_s[cur][pos * 64 + gg * 8];
                sc[ni] = __builtin_amdgcn_mfma_f32_16x16x32_bf16(
                    kf, aq[kst], sc[ni], 0, 0, 0);
            }
        }
        __builtin_amdgcn_s_setprio(0);

        // ---- causal mask: only on the diagonal tile
        if (j == qt) {
            int qg = qt * 64 + wave * 16 + m16;
#pragma unroll
            for (int ni = 0; ni < 4; ni++)
#pragma unroll
                for (int r = 0; r < 4; r++) {
                    int kp = kt0 + ni * 16 + quad * 4 + r;
                    if (kp > qg) sc[ni][r] = -1e9f;
                }
        }

        // ---- p = exp2(s); accumulate l; pack bf16 dwords in-register.
        unsigned int pd[4][2];
        {
            float ls0 = 0.f, ls1 = 0.f;
#pragma unroll
            for (int ni = 0; ni < 4; ni++) {
                float p0 = __builtin_amdgcn_exp2f(sc[ni][0]);
                float p1 = __builtin_amdgcn_exp2f(sc[ni][1]);
                float p2 = __builtin_amdgcn_exp2f(sc[ni][2]);
                float p3 = __builtin_amdgcn_exp2f(sc[ni][3]);
                union { bf16x4 h; unsigned int u[2]; } cv;
                cv.h[0] = (bf16)p0; cv.h[1] = (bf16)p1;
                cv.h[2] = (bf16)p2; cv.h[3] = (bf16)p3;
                pd[ni][0] = cv.u[0];
                pd[ni][1] = cv.u[1];
                ls0 += p0 + p1;
                ls1 += p2 + p3;
            }
            l_acc += ls0 + ls1;
        }

        // ---- O^T += (P @ V)^T, natural k order via p32+p16 double swap
#pragma unroll
        for (int kst = 0; kst < 2; kst++) {
            unsigned int x0 = pd[2 * kst][0],     y0 = pd[2 * kst][1];
            unsigned int x1 = pd[2 * kst + 1][0], y1 = pd[2 * kst + 1][1];
            asm("v_permlane32_swap_b32 %0, %1" : "+v"(x0), "+v"(x1));
            asm("v_permlane32_swap_b32 %0, %1" : "+v"(y0), "+v"(y1));
            asm("v_permlane16_swap_b32 %0, %1" : "+v"(x0), "+v"(x1));
            asm("v_permlane16_swap_b32 %0, %1" : "+v"(y0), "+v"(y1));
            union { unsigned int u[4]; bf16x8 v; } pk;
            pk.u[0] = x0; pk.u[1] = y0; pk.u[2] = x1; pk.u[3] = y1;
            bf16x8 ap = pk.v;
            __builtin_amdgcn_s_setprio(1);
#pragma unroll
            for (int di = 0; di < 4; di++) {
                int d = di * 16 + m16;
                int gg = (kst * 4 + quad) ^ (d & 7);
                bf16x8 vf = *(const bf16x8*)&Vt_s[cur][d * 64 + gg * 8];
                o[di] = __builtin_amdgcn_mfma_f32_16x16x32_bf16(
                    vf, ap, o[di], 0, 0, 0);
            }
            __builtin_amdgcn_s_setprio(0);
        }
    }

    // ---- final l reduction + normalize + write ctx [B,S,1024] bf16
    int b = bh >> 4, h = bh & 15;
    float l = l_acc;
    l += __shfl_xor(l, 16);
    l += __shfl_xor(l, 32);
    float rl = 1.0f / l;
    int s = qt * 64 + wave * 16 + m16;
#pragma unroll
    for (int di = 0; di < 4; di++) {
        bf16x4 pk;
#pragma unroll
        for (int r = 0; r < 4; r++) pk[r] = (bf16)(o[di][r] * rl);
        *(bf16x4*)(ctx + ((size_t)b * S_LEN + s) * D_MODEL
                   + h * DHEAD + di * 16 + quad * 4) = pk;
    }
}

// ================================ launch =====================================
extern "C" void kernel_launch(void* const* d_in, const int* in_sizes, int n_in,
                              void* d_out, int out_size, void* d_ws, size_t ws_size,
                              hipStream_t stream) {
    const float* x  = (const float*)d_in[0];
    const float* Wq = (const float*)d_in[1];
    const float* bq = (const float*)d_in[2];
    const float* Wk = (const float*)d_in[3];
    const float* bk = (const float*)d_in[4];
    const float* Wv = (const float*)d_in[5];
    const float* bv = (const float*)d_in[6];
    const float* Wo = (const float*)d_in[7];
    const float* bo = (const float*)d_in[8];
    float* out = (float*)d_out;

    char* ws = (char*)d_ws;
    const size_t MB = 1u << 20;
    bf16* xb  = (bf16*)(ws + 0);         // 8 MB  [4096,1024]
    bf16* Wt  = (bf16*)(ws + 8  * MB);   // 8 MB  [4][1024][1024]
    bf16* Qb  = (bf16*)(ws + 16 * MB);   // 8 MB  [B,H,S,64]  (pre-scaled by QSCALE)
    bf16* Kb  = (bf16*)(ws + 24 * MB);   // 8 MB  [B,H,S,64]
    bf16* Vtb = (bf16*)(ws + 32 * MB);   // 8 MB  [B,H,64,S]
    bf16* ctx = (bf16*)(ws + 0);         // reuse xb region (dead after QKV GEMM)

    prep_kernel<<<dim3(32, 32, 5), dim3(32, 8), 0, stream>>>(x, Wq, Wk, Wv, Wo,
                                                             xb, Wt);
    gemm0_kernel<<<dim3(192), 512, 0, stream>>>(xb, Wt, bq, bk, bv,
                                                Qb, Kb, Vtb);
    attn_kernel<<<dim3(32, 32), 256, 0, stream>>>(Qb, Kb, Vtb, ctx);
    gemm1_kernel<<<dim3(512), 512, 0, stream>>>(ctx, Wt + 3 * 1024 * 1024,
                                                bo, out);
}